// Round 5
// baseline (264.582 us; speedup 1.0000x reference)
//
#include <hip/hip_runtime.h>
#include <math.h>

// LocalSpatialEncoding: out[p=(n,k), :] = [ MLP(concat(o, nb, o-nb, |o-nb|)) , features[n] ]
//   MLP: relu(c @ W1 + b1) @ W2 + b2,  c:10, hidden:32, D:64. Row = 128 f32 = 512 B.
//
// Round 5 structure:
//  - 1 thread per row; 4 waves/block, wave owns 64 consecutive rows.
//  - Weights in LDS, read with wave-uniform addresses -> broadcast ds_read_b128
//    (no SGPR pressure, short pipelined latency).
//  - enc staged in wave-PRIVATE LDS tile in TWO 32-column passes ([64][36] f32
//    per wave = 36.9 KB/block total) -> 46.7 KB LDS -> 3 blocks/CU (12 waves/CU,
//    +50% vs round 4). 32 cols = 128 B/row/pass keeps stores line-complete.
//  - No block barrier in hot path: wave-local s_waitcnt lgkmcnt(0) fences the
//    wave-private tile (writes->reads and reads->next-pass writes).
//  - f4 ext-vector math -> v_pk_fma_f32, ~half the VALU issue.

#define HID 32
#define DF  64
#define RS  36   // tile row stride in floats (32 + 4 pad; 16B-aligned, bank-spread)

typedef float f4 __attribute__((ext_vector_type(4)));

__global__ __launch_bounds__(256) void lse_kernel(
    const float* __restrict__ coords,    // (N,3)
    const float* __restrict__ features,  // (N,64)
    const float* __restrict__ W1,        // (10,32)
    const float* __restrict__ b1,        // (32,)
    const float* __restrict__ W2,        // (32,64)
    const float* __restrict__ b2,        // (64,)
    const int*   __restrict__ nidx,      // (N,K)
    float* __restrict__ out,             // (N,K,128)
    long long total, int K, int kshift)
{
    __shared__ alignas(16) float sW1[10 * HID];
    __shared__ alignas(16) float sb1[HID];
    __shared__ alignas(16) float sW2[HID * DF];
    __shared__ alignas(16) float sb2[DF];
    __shared__ alignas(16) float tile[4][64][RS];

    const int t = threadIdx.x;
    {   // one-time weight staging (vectorized), only block-wide barrier
        f4* sW2v = (f4*)sW2;
        const f4* W2v = (const f4*)W2;
        for (int i = t; i < HID * DF / 4; i += 256) sW2v[i] = W2v[i];
        if (t < 80) ((f4*)sW1)[t] = ((const f4*)W1)[t];
        if (t >= 128 && t < 136) ((f4*)sb1)[t - 128] = ((const f4*)b1)[t - 128];
        if (t >= 160 && t < 176) ((f4*)sb2)[t - 160] = ((const f4*)b2)[t - 160];
    }
    __syncthreads();

    const int wv = t >> 6;
    const int l  = t & 63;
    const long long pbase = (long long)blockIdx.x * 256 + (long long)wv * 64;
    const long long p = pbase + l;
    const bool valid = p < total;

    // ---- h = relu(c @ W1 + b1) ----
    float h[HID];
    if (valid) {
        const int n = (kshift >= 0) ? (int)(p >> kshift) : (int)(p / K);
        const int j = nidx[p];
        const float ox = coords[3 * n + 0], oy = coords[3 * n + 1], oz = coords[3 * n + 2];
        const float nx = coords[3 * j + 0], ny = coords[3 * j + 1], nz = coords[3 * j + 2];
        const float rx = ox - nx, ry = oy - ny, rz = oz - nz;
        const float dist = sqrtf(rx * rx + ry * ry + rz * rz);
        const float c[10] = {ox, oy, oz, nx, ny, nz, rx, ry, rz, dist};

#pragma unroll
        for (int j0 = 0; j0 < HID; j0 += 4) {
            f4 acc = *(const f4*)&sb1[j0];
#pragma unroll
            for (int cc = 0; cc < 10; ++cc) {
                const f4 w = *(const f4*)&sW1[cc * HID + j0];
                acc += c[cc] * w;                 // broadcast ds_read, pk-fma
            }
            h[j0 + 0] = fmaxf(acc[0], 0.0f);
            h[j0 + 1] = fmaxf(acc[1], 0.0f);
            h[j0 + 2] = fmaxf(acc[2], 0.0f);
            h[j0 + 3] = fmaxf(acc[3], 0.0f);
        }
    }

    // ---- enc = h @ W2 + b2, two 32-column passes through wave-private tile ----
    const int q = l & 7;     // f4 slot within 128 B half-row
    const int g = l >> 3;    // row group
#pragma unroll
    for (int pass = 0; pass < 2; ++pass) {
        if (valid) {
#pragma unroll
            for (int cg = 0; cg < 32; cg += 4) {
                const int col = pass * 32 + cg;
                f4 acc = *(const f4*)&sb2[col];
#pragma unroll
                for (int jj = 0; jj < HID; ++jj) {
                    const f4 w = *(const f4*)&sW2[jj * DF + col];  // broadcast
                    acc += h[jj] * w;
                }
                *(f4*)&tile[wv][l][cg] = acc;
            }
        }
        // wave-local fence: drain tile writes before cross-lane reads
        asm volatile("s_waitcnt lgkmcnt(0)" ::: "memory");
        __builtin_amdgcn_sched_barrier(0);

        // store this 128 B half of each row: 8 lanes/row, 8 rows/iter (line-complete)
#pragma unroll
        for (int i = 0; i < 8; ++i) {
            const int r = 8 * i + g;
            const long long pr = pbase + r;
            if (pr < total) {
                const f4 enc = *(const f4*)&tile[wv][r][4 * q];
                __builtin_nontemporal_store(
                    enc, (f4*)(out + pr * (2 * DF) + pass * 32 + 4 * q));
            }
        }
        if (pass == 0) {  // drain tile reads before pass-1 overwrites it
            asm volatile("s_waitcnt lgkmcnt(0)" ::: "memory");
            __builtin_amdgcn_sched_barrier(0);
        }
    }

    // ---- features half: global -> global, 16 lanes/row (line-complete) ----
    const int q16 = l & 15;
    const int g4  = l >> 4;
#pragma unroll 4
    for (int i = 0; i < 16; ++i) {
        const int r = 4 * i + g4;
        const long long pr = pbase + r;
        if (pr < total) {
            const int nr = (kshift >= 0) ? (int)(pr >> kshift) : (int)(pr / K);
            const f4 f = *(const f4*)(features + (long long)nr * DF + 4 * q16);
            __builtin_nontemporal_store(f, (f4*)(out + pr * (2 * DF) + DF + 4 * q16));
        }
    }
}

extern "C" void kernel_launch(void* const* d_in, const int* in_sizes, int n_in,
                              void* d_out, int out_size, void* d_ws, size_t ws_size,
                              hipStream_t stream) {
    const float* coords   = (const float*)d_in[0];
    const float* features = (const float*)d_in[1];
    const float* W1       = (const float*)d_in[2];
    const float* b1       = (const float*)d_in[3];
    const float* W2       = (const float*)d_in[4];
    const float* b2       = (const float*)d_in[5];
    const int*   nidx     = (const int*)d_in[6];

    const int N = in_sizes[0] / 3;              // coords (N,3)
    const int K = in_sizes[6] / N;              // neighbor_idx (N,K)
    const long long total = (long long)N * K;
    const int kshift = ((K & (K - 1)) == 0) ? __builtin_ctz(K) : -1;

    float* out = (float*)d_out;

    const int block = 256;                      // 4 waves x 64 rows
    const long long grid = (total + 255) / 256;
    lse_kernel<<<(unsigned)grid, block, 0, stream>>>(
        coords, features, W1, b1, W2, b2, nidx, out, total, K, kshift);
}

// Round 6
// 241.796 us; speedup vs baseline: 1.0942x; 1.0942x over previous
//
#include <hip/hip_runtime.h>
#include <math.h>

// LocalSpatialEncoding: out[p=(n,k), :] = [ MLP(concat(o, nb, o-nb, |o-nb|)) , features[n] ]
//   MLP: relu(c @ W1 + b1) @ W2 + b2,  c:10, hidden:32, D:64. Row = 128 f32 = 512 B.
//
// Round 6:
//  - 1 thread per row; 4 waves/block; wave owns 64 consecutive rows.
//  - Weights via GLOBAL uniform-address f4 reads -> s_load_dwordx4 (scalar pipe,
//    sK$-cached, zero VALU/LDS cost) + v_pk_fma_f32.  (Round 5 proved LDS-broadcast
//    weights regress: ~590 ds_read/wave serialize on the per-CU LDS pipe.)
//  - enc transposed through a wave-private XOR-SWIZZLED tile, two 32-col passes:
//    logical slot s of row l lives at physical slot s^(l&7), row stride 32 dwords.
//    -> conflict-free ds_write_b128/ds_read_b128 (each 8-lane group covers 8
//    distinct bank quartets), and tile is 32 KB -> 5 blocks/CU (launch_bounds 5).
//  - Stores: 8 lanes x f4 = one full 128 B line per instruction (no write amp).
//  - Wave-local s_waitcnt lgkmcnt(0) fences only (tile is wave-private); no
//    sched_barrier, no block barrier -> pass-1 FMAs overlap pass-0 stores.

#define HID 32
#define DF  64

typedef float f4 __attribute__((ext_vector_type(4)));

__global__ __launch_bounds__(256, 5) void lse_kernel(
    const float* __restrict__ coords,    // (N,3)
    const float* __restrict__ features,  // (N,64)
    const float* __restrict__ W1,        // (10,32)
    const float* __restrict__ b1,        // (32,)
    const float* __restrict__ W2,        // (32,64)
    const float* __restrict__ b2,        // (64,)
    const int*   __restrict__ nidx,      // (N,K)
    float* __restrict__ out,             // (N,K,128)
    long long total, int K, int kshift)
{
    __shared__ alignas(16) float tile[4][64][32];   // 32 KB, wave-private [64][32] each

    const int t  = threadIdx.x;
    const int wv = t >> 6;
    const int l  = t & 63;
    const long long pbase = (long long)blockIdx.x * 256 + (long long)wv * 64;
    const long long p = pbase + l;
    const bool valid = p < total;

    const f4* W1v = (const f4*)W1;   // 80 f4
    const f4* W2v = (const f4*)W2;   // 512 f4
    const f4* b1v = (const f4*)b1;
    const f4* b2v = (const f4*)b2;

    // ---- h = relu(c @ W1 + b1): uniform W1 addrs -> s_load, pk-fma ----
    float h[HID];
    if (valid) {
        const int n = (kshift >= 0) ? (int)(p >> kshift) : (int)(p / K);
        const int j = nidx[p];
        const float ox = coords[3 * n + 0], oy = coords[3 * n + 1], oz = coords[3 * n + 2];
        const float nx = coords[3 * j + 0], ny = coords[3 * j + 1], nz = coords[3 * j + 2];
        const float rx = ox - nx, ry = oy - ny, rz = oz - nz;
        const float dist = sqrtf(rx * rx + ry * ry + rz * rz);
        const float c[10] = {ox, oy, oz, nx, ny, nz, rx, ry, rz, dist};

#pragma unroll
        for (int j0 = 0; j0 < HID / 4; ++j0) {
            f4 acc = b1v[j0];
#pragma unroll
            for (int cc = 0; cc < 10; ++cc)
                acc += c[cc] * W1v[cc * (HID / 4) + j0];   // s_load_dwordx4 + v_pk_fma
            h[4 * j0 + 0] = fmaxf(acc[0], 0.0f);
            h[4 * j0 + 1] = fmaxf(acc[1], 0.0f);
            h[4 * j0 + 2] = fmaxf(acc[2], 0.0f);
            h[4 * j0 + 3] = fmaxf(acc[3], 0.0f);
        }
    }

    // ---- enc = h @ W2 + b2: two 32-col passes through swizzled wave tile ----
    const int q = l & 7;     // f4 slot within 128 B half-row (store phase)
    const int g = l >> 3;    // row group (store phase)
#pragma unroll
    for (int pass = 0; pass < 2; ++pass) {
        if (valid) {
#pragma unroll
            for (int s = 0; s < 8; ++s) {                 // logical f4 slot
                const int col4 = pass * 8 + s;            // f4-col index in [0,16)
                f4 acc = b2v[col4];
#pragma unroll
                for (int jj = 0; jj < HID; ++jj)
                    acc += h[jj] * W2v[jj * (DF / 4) + col4];   // s_load + pk-fma
                // swizzled write: physical slot = s ^ (l&7)
                *(f4*)&tile[wv][l][4 * (s ^ (l & 7))] = acc;
            }
        }
        // wave-local fence: drain tile writes before cross-lane reads
        asm volatile("s_waitcnt lgkmcnt(0)" ::: "memory");

        // store this 128 B half of 8 rows/iter: 8 lanes x f4 = full line
#pragma unroll
        for (int i = 0; i < 8; ++i) {
            const int r = 8 * i + g;
            const long long pr = pbase + r;
            if (pr < total) {
                const f4 enc = *(const f4*)&tile[wv][r][4 * (q ^ (r & 7))];
                __builtin_nontemporal_store(
                    enc, (f4*)(out + pr * (2 * DF) + pass * 32 + 4 * q));
            }
        }
        if (pass == 0) {  // drain tile reads before pass 1 overwrites the tile
            asm volatile("s_waitcnt lgkmcnt(0)" ::: "memory");
        }
    }

    // ---- features half: global -> global, 16 lanes/row (line-complete) ----
    const int q16 = l & 15;
    const int g4  = l >> 4;
#pragma unroll 4
    for (int i = 0; i < 16; ++i) {
        const int r = 4 * i + g4;
        const long long pr = pbase + r;
        if (pr < total) {
            const int nr = (kshift >= 0) ? (int)(pr >> kshift) : (int)(pr / K);
            const f4 f = *(const f4*)(features + (long long)nr * DF + 4 * q16);
            __builtin_nontemporal_store(f, (f4*)(out + pr * (2 * DF) + DF + 4 * q16));
        }
    }
}

extern "C" void kernel_launch(void* const* d_in, const int* in_sizes, int n_in,
                              void* d_out, int out_size, void* d_ws, size_t ws_size,
                              hipStream_t stream) {
    const float* coords   = (const float*)d_in[0];
    const float* features = (const float*)d_in[1];
    const float* W1       = (const float*)d_in[2];
    const float* b1       = (const float*)d_in[3];
    const float* W2       = (const float*)d_in[4];
    const float* b2       = (const float*)d_in[5];
    const int*   nidx     = (const int*)d_in[6];

    const int N = in_sizes[0] / 3;              // coords (N,3)
    const int K = in_sizes[6] / N;              // neighbor_idx (N,K)
    const long long total = (long long)N * K;
    const int kshift = ((K & (K - 1)) == 0) ? __builtin_ctz(K) : -1;

    float* out = (float*)d_out;

    const int block = 256;                      // 4 waves x 64 rows
    const long long grid = (total + 255) / 256;
    lse_kernel<<<(unsigned)grid, block, 0, stream>>>(
        coords, features, W1, b1, W2, b2, nidx, out, total, K, kshift);
}

// Round 7
// 179.204 us; speedup vs baseline: 1.4764x; 1.3493x over previous
//
#include <hip/hip_runtime.h>
#include <math.h>

// LocalSpatialEncoding split into two BW-bound kernels:
//   E: out[p, 0:64]   = relu(c @ W1 + b1) @ W2 + b2   (compute + LDS transpose)
//   F: out[p, 64:128] = features[p / K]               (pure streaming broadcast)
// Both use instruction-level line-complete NT stores (every store instruction's
// lanes cover whole 128 B lines) — this eliminated round 1's 2.5x write amp.
//
// Round 7 notes:
//  - round 5 proved LDS-broadcast weights regress (per-CU LDS pipe serializes);
//    weights stay on the scalar pipe (uniform-address f4 -> s_load_dwordx4).
//  - round 6 proved wave-local lgkmcnt(0)+"memory" fences regress (lgkmcnt also
//    drains SMEM; clobber kills W2 SGPR reuse). Back to plain __syncthreads.
//  - no min-waves launch_bounds cap (round 6's (256,5) risked VGPR squeeze).
//  - XOR-swizzled wave-private tile (32 KB/block): slot s of row l at s^(l&7),
//    row stride 32 dwords -> conflict-free ds_write_b128/ds_read_b128.

#define HID 32
#define DF  64

typedef float f4 __attribute__((ext_vector_type(4)));

__global__ __launch_bounds__(256) void lse_enc_kernel(
    const float* __restrict__ coords,    // (N,3)
    const float* __restrict__ W1,        // (10,32)
    const float* __restrict__ b1,        // (32,)
    const float* __restrict__ W2,        // (32,64)
    const float* __restrict__ b2,        // (64,)
    const int*   __restrict__ nidx,      // (N,K)
    float* __restrict__ out,             // (N,K,128)
    long long total, int K, int kshift)
{
    __shared__ alignas(16) float tile[4][64][32];   // 32 KB; wave-private [64][32]

    const int t  = threadIdx.x;
    const int wv = t >> 6;
    const int l  = t & 63;
    const long long pbase = (long long)blockIdx.x * 256 + (long long)wv * 64;
    const long long p = pbase + l;
    const bool valid = p < total;

    const f4* W1v = (const f4*)W1;   // 80 f4
    const f4* W2v = (const f4*)W2;   // 512 f4
    const f4* b1v = (const f4*)b1;
    const f4* b2v = (const f4*)b2;

    // ---- h = relu(c @ W1 + b1): uniform W1 addrs -> s_load_dwordx4 + pk-fma ----
    float h[HID];
    if (valid) {
        const int n = (kshift >= 0) ? (int)(p >> kshift) : (int)(p / K);
        const int j = nidx[p];
        const float ox = coords[3 * n + 0], oy = coords[3 * n + 1], oz = coords[3 * n + 2];
        const float nx = coords[3 * j + 0], ny = coords[3 * j + 1], nz = coords[3 * j + 2];
        const float rx = ox - nx, ry = oy - ny, rz = oz - nz;
        const float dist = sqrtf(rx * rx + ry * ry + rz * rz);
        const float c[10] = {ox, oy, oz, nx, ny, nz, rx, ry, rz, dist};

#pragma unroll
        for (int j0 = 0; j0 < HID / 4; ++j0) {
            f4 acc = b1v[j0];
#pragma unroll
            for (int cc = 0; cc < 10; ++cc)
                acc += c[cc] * W1v[cc * (HID / 4) + j0];
            h[4 * j0 + 0] = fmaxf(acc[0], 0.0f);
            h[4 * j0 + 1] = fmaxf(acc[1], 0.0f);
            h[4 * j0 + 2] = fmaxf(acc[2], 0.0f);
            h[4 * j0 + 3] = fmaxf(acc[3], 0.0f);
        }
    }

    // ---- enc = h @ W2 + b2: two 32-col passes through swizzled wave tile ----
    const int q = l & 7;     // f4 slot within the 128 B half-row (store phase)
    const int g = l >> 3;    // row group (store phase)
#pragma unroll
    for (int pass = 0; pass < 2; ++pass) {
        if (pass == 1) __syncthreads();   // pass-0 tile reads done before overwrite
        if (valid) {
#pragma unroll
            for (int s = 0; s < 8; ++s) {
                const int col4 = pass * 8 + s;            // f4-col in [0,16)
                f4 acc = b2v[col4];
#pragma unroll
                for (int jj = 0; jj < HID; ++jj)
                    acc += h[jj] * W2v[jj * (DF / 4) + col4];
                *(f4*)&tile[wv][l][4 * (s ^ (l & 7))] = acc;   // swizzled write
            }
        }
        __syncthreads();                  // tile writes visible before reads

        // 8 lanes x f4 = one full 128 B line per store instruction
#pragma unroll
        for (int i = 0; i < 8; ++i) {
            const int r = 8 * i + g;
            const long long pr = pbase + r;
            if (pr < total) {
                const f4 enc = *(const f4*)&tile[wv][r][4 * (q ^ (r & 7))];
                __builtin_nontemporal_store(
                    enc, (f4*)(out + pr * (2 * DF) + pass * 32 + 4 * q));
            }
        }
    }
}

__global__ __launch_bounds__(256) void lse_feat_kernel(
    const float* __restrict__ features,  // (N,64)
    float* __restrict__ out,             // (N,K,128)
    long long total, int K, int kshift)
{
    // One f4 per (row, slot): 16 consecutive lanes cover a row's 256 B features
    // half -> 2 full 128 B lines per store instruction. Pure streaming.
    const long long nf4 = total * 16;
    const long long stride = (long long)gridDim.x * 256;
    for (long long idx = (long long)blockIdx.x * 256 + threadIdx.x;
         idx < nf4; idx += stride) {
        const long long pr = idx >> 4;
        const int slot = (int)(idx & 15);
        const int n = (kshift >= 0) ? (int)(pr >> kshift) : (int)(pr / K);
        const f4 f = *(const f4*)(features + (long long)n * DF + 4 * slot);
        __builtin_nontemporal_store(f, (f4*)(out + pr * (2 * DF) + DF + 4 * slot));
    }
}

extern "C" void kernel_launch(void* const* d_in, const int* in_sizes, int n_in,
                              void* d_out, int out_size, void* d_ws, size_t ws_size,
                              hipStream_t stream) {
    const float* coords   = (const float*)d_in[0];
    const float* features = (const float*)d_in[1];
    const float* W1       = (const float*)d_in[2];
    const float* b1       = (const float*)d_in[3];
    const float* W2       = (const float*)d_in[4];
    const float* b2       = (const float*)d_in[5];
    const int*   nidx     = (const int*)d_in[6];

    const int N = in_sizes[0] / 3;              // coords (N,3)
    const int K = in_sizes[6] / N;              // neighbor_idx (N,K)
    const long long total = (long long)N * K;
    const int kshift = ((K & (K - 1)) == 0) ? __builtin_ctz(K) : -1;

    float* out = (float*)d_out;

    const long long grid_e = (total + 255) / 256;   // 4 waves x 64 rows
    lse_enc_kernel<<<(unsigned)grid_e, 256, 0, stream>>>(
        coords, W1, b1, W2, b2, nidx, out, total, K, kshift);

    const long long nf4 = total * 16;
    long long grid_f = (nf4 + 255) / 256;
    if (grid_f > 8192) grid_f = 8192;               // grid-stride
    lse_feat_kernel<<<(unsigned)grid_f, 256, 0, stream>>>(
        features, out, total, K, kshift);
}

// Round 8
// 162.274 us; speedup vs baseline: 1.6305x; 1.1043x over previous
//
#include <hip/hip_runtime.h>
#include <math.h>

// LocalSpatialEncoding: out[p=(n,k), :] = [ MLP(concat(o, nb, o-nb, |o-nb|)) , features[n] ]
//   MLP: relu(c @ W1 + b1) @ W2 + b2,  c:10, hidden:32, D:64. Row = 128 f32 = 512 B.
//
// Round 8: single fused kernel (round 7 split serialized enc->feat and wrote
// each row at 50% density per sweep; fusing interleaves enc+feat lines so each
// wave emits one dense 64-row x 512 B write stream).
//  - 1 thread per row; 4 waves/block; wave owns 64 consecutive rows.
//  - Weights on scalar pipe: uniform-address f4 reads -> s_load_dwordx4 + pk-fma
//    (round 5 proved LDS-broadcast weights regress).
//  - enc transposed via wave-private XOR-swizzled tile (32 KB/block, 5 blocks/CU),
//    two 32-col passes; conflict-free ds_write_b128/ds_read_b128
//    (physical f4 slot = s ^ (l&7), row stride 32 dwords).
//  - Every store instruction's 8-lane groups cover full 128 B lines (round 1's
//    2.5x write amp fix). Plain __syncthreads between passes (round 6 proved
//    lgkmcnt-fences-with-clobber regress).

#define HID 32
#define DF  64

typedef float f4 __attribute__((ext_vector_type(4)));

__global__ __launch_bounds__(256) void lse_kernel(
    const float* __restrict__ coords,    // (N,3)
    const float* __restrict__ features,  // (N,64)
    const float* __restrict__ W1,        // (10,32)
    const float* __restrict__ b1,        // (32,)
    const float* __restrict__ W2,        // (32,64)
    const float* __restrict__ b2,        // (64,)
    const int*   __restrict__ nidx,      // (N,K)
    float* __restrict__ out,             // (N,K,128)
    long long total, int K, int kshift)
{
    __shared__ alignas(16) float tile[4][64][32];   // 32 KB; wave-private [64][32]

    const int t  = threadIdx.x;
    const int wv = t >> 6;
    const int l  = t & 63;
    const long long pbase = (long long)blockIdx.x * 256 + (long long)wv * 64;
    const long long p = pbase + l;
    const bool valid = p < total;

    const f4* W1v = (const f4*)W1;   // 80 f4
    const f4* W2v = (const f4*)W2;   // 512 f4
    const f4* b1v = (const f4*)b1;
    const f4* b2v = (const f4*)b2;

    // ---- h = relu(c @ W1 + b1): uniform W1 addrs -> s_load_dwordx4 + pk-fma ----
    float h[HID];
    if (valid) {
        const int n = (kshift >= 0) ? (int)(p >> kshift) : (int)(p / K);
        const int j = nidx[p];
        const float ox = coords[3 * n + 0], oy = coords[3 * n + 1], oz = coords[3 * n + 2];
        const float nx = coords[3 * j + 0], ny = coords[3 * j + 1], nz = coords[3 * j + 2];
        const float rx = ox - nx, ry = oy - ny, rz = oz - nz;
        const float dist = sqrtf(rx * rx + ry * ry + rz * rz);
        const float c[10] = {ox, oy, oz, nx, ny, nz, rx, ry, rz, dist};

#pragma unroll
        for (int j0 = 0; j0 < HID / 4; ++j0) {
            f4 acc = b1v[j0];
#pragma unroll
            for (int cc = 0; cc < 10; ++cc)
                acc += c[cc] * W1v[cc * (HID / 4) + j0];
            h[4 * j0 + 0] = fmaxf(acc[0], 0.0f);
            h[4 * j0 + 1] = fmaxf(acc[1], 0.0f);
            h[4 * j0 + 2] = fmaxf(acc[2], 0.0f);
            h[4 * j0 + 3] = fmaxf(acc[3], 0.0f);
        }
    }

    // ---- enc = h @ W2 + b2 (two 32-col passes) + interleaved feat stores ----
    const int q = l & 7;     // f4 slot within a 128 B line (store phase)
    const int g = l >> 3;    // row group (store phase)
#pragma unroll
    for (int pass = 0; pass < 2; ++pass) {
        if (pass == 1) __syncthreads();   // pass-0 tile reads done before overwrite
        if (valid) {
#pragma unroll
            for (int s = 0; s < 8; ++s) {
                const int col4 = pass * 8 + s;            // f4-col in [0,16)
                f4 acc = b2v[col4];
#pragma unroll
                for (int jj = 0; jj < HID; ++jj)
                    acc += h[jj] * W2v[jj * (DF / 4) + col4];
                *(f4*)&tile[wv][l][4 * (s ^ (l & 7))] = acc;   // swizzled write
            }
        }
        __syncthreads();                  // tile writes visible before reads

        // Store phase: 8 rows/iter; per row, this pass's enc line (128 B) and
        // the matching feat line (128 B). All stores line-complete.
#pragma unroll
        for (int i = 0; i < 8; ++i) {
            const int r = 8 * i + g;
            const long long pr = pbase + r;
            if (pr < total) {
                float* orow = out + pr * (2 * DF);
                const f4 enc = *(const f4*)&tile[wv][r][4 * (q ^ (r & 7))];
                __builtin_nontemporal_store(enc, (f4*)(orow + pass * 32 + 4 * q));

                const int nr = (kshift >= 0) ? (int)(pr >> kshift) : (int)(pr / K);
                const f4 f = *(const f4*)(features + (long long)nr * DF + pass * 32 + 4 * q);
                __builtin_nontemporal_store(f, (f4*)(orow + DF + pass * 32 + 4 * q));
            }
        }
    }
}

extern "C" void kernel_launch(void* const* d_in, const int* in_sizes, int n_in,
                              void* d_out, int out_size, void* d_ws, size_t ws_size,
                              hipStream_t stream) {
    const float* coords   = (const float*)d_in[0];
    const float* features = (const float*)d_in[1];
    const float* W1       = (const float*)d_in[2];
    const float* b1       = (const float*)d_in[3];
    const float* W2       = (const float*)d_in[4];
    const float* b2       = (const float*)d_in[5];
    const int*   nidx     = (const int*)d_in[6];

    const int N = in_sizes[0] / 3;              // coords (N,3)
    const int K = in_sizes[6] / N;              // neighbor_idx (N,K)
    const long long total = (long long)N * K;
    const int kshift = ((K & (K - 1)) == 0) ? __builtin_ctz(K) : -1;

    float* out = (float*)d_out;

    const int block = 256;                      // 4 waves x 64 rows
    const long long grid = (total + 255) / 256;
    lse_kernel<<<(unsigned)grid, block, 0, stream>>>(
        coords, features, W1, b1, W2, b2, nidx, out, total, K, kshift);
}

// Round 9
// 161.211 us; speedup vs baseline: 1.6412x; 1.0066x over previous
//
#include <hip/hip_runtime.h>
#include <math.h>

// LocalSpatialEncoding: out[p=(n,k), :] = [ MLP(concat(o, nb, o-nb, |o-nb|)) , features[n] ]
//   MLP: relu(c @ W1 + b1) @ W2 + b2,  c:10, hidden:32, D:64. Row = 128 f32 = 512 B.
//
// Round 9: single fused kernel; DENSE write stream.
//  - 1 thread per row; 4 waves/block; wave owns 64 consecutive rows.
//  - Weights on scalar pipe (uniform f4 -> s_load_dwordx4 + v_pk_fma); r5 proved
//    LDS-broadcast weights regress.
//  - enc transposed via wave-private XOR-swizzled 32 KB tile, two 32-col passes
//    (conflict-free ds_write_b128/ds_read_b128: physical slot = s ^ (l&7)).
//  - NEW: pass-0 tile reads buffered in regs (e0[8], statically indexed), single
//    store loop after pass 1 writes all 4 lines of each row back-to-back ->
//    fully dense 4 KB per wave-iteration (r8 wrote each row at 50% density per
//    pass -> DRAM page-locality loss).
//  - All stores line-complete NT (8 lanes x f4 = 128 B). Plain __syncthreads
//    (r6 proved lgkmcnt+clobber fences regress).

#define HID 32
#define DF  64

typedef float f4 __attribute__((ext_vector_type(4)));

__global__ __launch_bounds__(256) void lse_kernel(
    const float* __restrict__ coords,    // (N,3)
    const float* __restrict__ features,  // (N,64)
    const float* __restrict__ W1,        // (10,32)
    const float* __restrict__ b1,        // (32,)
    const float* __restrict__ W2,        // (32,64)
    const float* __restrict__ b2,        // (64,)
    const int*   __restrict__ nidx,      // (N,K)
    float* __restrict__ out,             // (N,K,128)
    long long total, int K, int kshift)
{
    __shared__ alignas(16) float tile[4][64][32];   // 32 KB; wave-private [64][32]

    const int t  = threadIdx.x;
    const int wv = t >> 6;
    const int l  = t & 63;
    const long long pbase = (long long)blockIdx.x * 256 + (long long)wv * 64;
    const long long p = pbase + l;
    const bool valid = p < total;

    const f4* W1v = (const f4*)W1;   // 80 f4
    const f4* W2v = (const f4*)W2;   // 512 f4
    const f4* b1v = (const f4*)b1;
    const f4* b2v = (const f4*)b2;

    // ---- h = relu(c @ W1 + b1) ----
    float h[HID];
    if (valid) {
        const int n = (kshift >= 0) ? (int)(p >> kshift) : (int)(p / K);
        const int j = nidx[p];
        const float ox = coords[3 * n + 0], oy = coords[3 * n + 1], oz = coords[3 * n + 2];
        const float nx = coords[3 * j + 0], ny = coords[3 * j + 1], nz = coords[3 * j + 2];
        const float rx = ox - nx, ry = oy - ny, rz = oz - nz;
        const float dist = sqrtf(rx * rx + ry * ry + rz * rz);
        const float c[10] = {ox, oy, oz, nx, ny, nz, rx, ry, rz, dist};

#pragma unroll
        for (int j0 = 0; j0 < HID / 4; ++j0) {
            f4 acc = b1v[j0];
#pragma unroll
            for (int cc = 0; cc < 10; ++cc)
                acc += c[cc] * W1v[cc * (HID / 4) + j0];
            h[4 * j0 + 0] = fmaxf(acc[0], 0.0f);
            h[4 * j0 + 1] = fmaxf(acc[1], 0.0f);
            h[4 * j0 + 2] = fmaxf(acc[2], 0.0f);
            h[4 * j0 + 3] = fmaxf(acc[3], 0.0f);
        }
    }

    const int q = l & 7;     // f4 slot within a 128 B line (store phase)
    const int g = l >> 3;    // row group (store phase)

    // ---- pass 0: enc cols 0..31 -> tile ----
    if (valid) {
#pragma unroll
        for (int s = 0; s < 8; ++s) {
            f4 acc = b2v[s];
#pragma unroll
            for (int jj = 0; jj < HID; ++jj)
                acc += h[jj] * W2v[jj * (DF / 4) + s];
            *(f4*)&tile[wv][l][4 * (s ^ (l & 7))] = acc;
        }
    }
    __syncthreads();

    // buffer my 8 pass-0 lines in regs (statically indexed; stays in VGPRs)
    f4 e0[8];
#pragma unroll
    for (int i = 0; i < 8; ++i) {
        const int r = 8 * i + g;
        e0[i] = *(const f4*)&tile[wv][r][4 * (q ^ (r & 7))];
    }
    __syncthreads();   // all pass-0 reads done before overwrite

    // ---- pass 1: enc cols 32..63 -> tile ----
    if (valid) {
#pragma unroll
        for (int s = 0; s < 8; ++s) {
            f4 acc = b2v[8 + s];
#pragma unroll
            for (int jj = 0; jj < HID; ++jj)
                acc += h[jj] * W2v[jj * (DF / 4) + 8 + s];
            *(f4*)&tile[wv][l][4 * (s ^ (l & 7))] = acc;
        }
    }
    __syncthreads();

    // ---- dense store loop: all 4 lines of each row back-to-back ----
    float* const obase = out + pbase * (2 * DF);
    if (kshift >= 0) {
        const long long nbase = pbase >> kshift;           // pbase % (1<<kshift) == 0
#pragma unroll
        for (int i = 0; i < 8; ++i) {
            const int r = 8 * i + g;
            if (pbase + r < total) {
                float* orow = obase + r * (2 * DF);
                const int nr = (int)(nbase + (r >> kshift));
                const float* frow = features + (long long)nr * DF;
                const f4 f0 = *(const f4*)(frow + 4 * q);
                const f4 f1 = *(const f4*)(frow + 32 + 4 * q);
                const f4 e1 = *(const f4*)&tile[wv][r][4 * (q ^ (r & 7))];
                __builtin_nontemporal_store(e0[i], (f4*)(orow + 4 * q));
                __builtin_nontemporal_store(e1,    (f4*)(orow + 32 + 4 * q));
                __builtin_nontemporal_store(f0,    (f4*)(orow + DF + 4 * q));
                __builtin_nontemporal_store(f1,    (f4*)(orow + DF + 32 + 4 * q));
            }
        }
    } else {
#pragma unroll
        for (int i = 0; i < 8; ++i) {
            const int r = 8 * i + g;
            const long long pr = pbase + r;
            if (pr < total) {
                float* orow = obase + r * (2 * DF);
                const int nr = (int)(pr / K);
                const float* frow = features + (long long)nr * DF;
                const f4 f0 = *(const f4*)(frow + 4 * q);
                const f4 f1 = *(const f4*)(frow + 32 + 4 * q);
                const f4 e1 = *(const f4*)&tile[wv][r][4 * (q ^ (r & 7))];
                __builtin_nontemporal_store(e0[i], (f4*)(orow + 4 * q));
                __builtin_nontemporal_store(e1,    (f4*)(orow + 32 + 4 * q));
                __builtin_nontemporal_store(f0,    (f4*)(orow + DF + 4 * q));
                __builtin_nontemporal_store(f1,    (f4*)(orow + DF + 32 + 4 * q));
            }
        }
    }
}

extern "C" void kernel_launch(void* const* d_in, const int* in_sizes, int n_in,
                              void* d_out, int out_size, void* d_ws, size_t ws_size,
                              hipStream_t stream) {
    const float* coords   = (const float*)d_in[0];
    const float* features = (const float*)d_in[1];
    const float* W1       = (const float*)d_in[2];
    const float* b1       = (const float*)d_in[3];
    const float* W2       = (const float*)d_in[4];
    const float* b2       = (const float*)d_in[5];
    const int*   nidx     = (const int*)d_in[6];

    const int N = in_sizes[0] / 3;              // coords (N,3)
    const int K = in_sizes[6] / N;              // neighbor_idx (N,K)
    const long long total = (long long)N * K;
    const int kshift = ((K & (K - 1)) == 0) ? __builtin_ctz(K) : -1;

    float* out = (float*)d_out;

    const int block = 256;                      // 4 waves x 64 rows
    const long long grid = (total + 255) / 256;
    lse_kernel<<<(unsigned)grid, block, 0, stream>>>(
        coords, features, W1, b1, W2, b2, nidx, out, total, K, kshift);
}

// Round 10
// 156.003 us; speedup vs baseline: 1.6960x; 1.0334x over previous
//
#include <hip/hip_runtime.h>
#include <math.h>

// LocalSpatialEncoding: out[p=(n,k), :] = [ MLP(concat(o, nb, o-nb, |o-nb|)) , features[n] ]
//   MLP: relu(c @ W1 + b1) @ W2 + b2,  c:10, hidden:32, D:64. Row = 128 f32 = 512 B.
//
// Round 10 (round-8 skeleton + latency/issue fixes):
//  - 1 thread per row; 4 waves/block; wave owns 64 consecutive rows.
//  - Weights on scalar pipe (uniform f4 -> s_load_dwordx4 + v_pk_fma).
//  - enc transposed via wave-private XOR-swizzled 32 KB tile, two 32-col passes,
//    conflict-free ds ops (physical f4 slot = s ^ (l&7)).
//  - NEW: FAST template path (total%256==0 && K==16): zero bounds guards, and
//    feat gathers DEDUPED (a thread's 8 rows span exactly 4 distinct n) and
//    PREFETCHED into regs before each pass's MLP (~1000 cyc of FMA hides L2
//    latency); the store loop touches registers + tile only.
//  - All out stores line-complete NT (8 lanes x f4 = full 128 B line).
//  - Plain __syncthreads (r6 proved lgkmcnt+clobber fences regress here).

#define HID 32
#define DF  64

typedef float f4 __attribute__((ext_vector_type(4)));

template<bool FAST>   // FAST: total % 256 == 0 && K == 16
__global__ __launch_bounds__(256) void lse_kernel(
    const float* __restrict__ coords,    // (N,3)
    const float* __restrict__ features,  // (N,64)
    const float* __restrict__ W1,        // (10,32)
    const float* __restrict__ b1,        // (32,)
    const float* __restrict__ W2,        // (32,64)
    const float* __restrict__ b2,        // (64,)
    const int*   __restrict__ nidx,      // (N,K)
    float* __restrict__ out,             // (N,K,128)
    long long total, int K, int kshift)
{
    __shared__ alignas(16) float tile[4][64][32];   // 32 KB; wave-private [64][32]

    const int t  = threadIdx.x;
    const int wv = t >> 6;
    const int l  = t & 63;
    const long long pbase = (long long)blockIdx.x * 256 + (long long)wv * 64;
    const long long p = pbase + l;
    const bool valid = FAST ? true : (p < total);

    const f4* W1v = (const f4*)W1;   // 80 f4
    const f4* W2v = (const f4*)W2;   // 512 f4
    const f4* b1v = (const f4*)b1;
    const f4* b2v = (const f4*)b2;

    const int q = l & 7;     // f4 slot within a 128 B line (store phase)
    const int g = l >> 3;    // row group (store phase)
    const long long nbase = FAST ? (pbase >> 4) : 0;

    // FAST: prefetch pass-0 feat lines (4 distinct rows, bytes [16q,16q+16))
    f4 F0[4];
    if (FAST) {
#pragma unroll
        for (int m = 0; m < 4; ++m)
            F0[m] = *(const f4*)(features + (nbase + m) * DF + 4 * q);
    }

    // ---- h = relu(c @ W1 + b1) ----
    float h[HID];
    if (valid) {
        const int n = FAST ? (int)(p >> 4)
                           : ((kshift >= 0) ? (int)(p >> kshift) : (int)(p / K));
        const int j = nidx[p];
        const float ox = coords[3 * n + 0], oy = coords[3 * n + 1], oz = coords[3 * n + 2];
        const float nx = coords[3 * j + 0], ny = coords[3 * j + 1], nz = coords[3 * j + 2];
        const float rx = ox - nx, ry = oy - ny, rz = oz - nz;
        const float dist = sqrtf(rx * rx + ry * ry + rz * rz);
        const float c[10] = {ox, oy, oz, nx, ny, nz, rx, ry, rz, dist};

#pragma unroll
        for (int j0 = 0; j0 < HID / 4; ++j0) {
            f4 acc = b1v[j0];
#pragma unroll
            for (int cc = 0; cc < 10; ++cc)
                acc += c[cc] * W1v[cc * (HID / 4) + j0];
            h[4 * j0 + 0] = fmaxf(acc[0], 0.0f);
            h[4 * j0 + 1] = fmaxf(acc[1], 0.0f);
            h[4 * j0 + 2] = fmaxf(acc[2], 0.0f);
            h[4 * j0 + 3] = fmaxf(acc[3], 0.0f);
        }
    }

    // ---- pass 0: enc cols 0..31 -> tile ----
    if (valid) {
#pragma unroll
        for (int s = 0; s < 8; ++s) {
            f4 acc = b2v[s];
#pragma unroll
            for (int jj = 0; jj < HID; ++jj)
                acc += h[jj] * W2v[jj * (DF / 4) + s];
            *(f4*)&tile[wv][l][4 * (s ^ (l & 7))] = acc;
        }
    }
    __syncthreads();

    // ---- pass-0 stores: enc line0 + feat line0 of 8 rows ----
#pragma unroll
    for (int i = 0; i < 8; ++i) {
        const int r = 8 * i + g;
        const long long pr = pbase + r;
        if (FAST || pr < total) {
            float* orow = out + pr * (2 * DF);
            const f4 enc = *(const f4*)&tile[wv][r][4 * (q ^ (r & 7))];
            __builtin_nontemporal_store(enc, (f4*)(orow + 4 * q));
            f4 f;
            if (FAST) f = F0[i >> 1];
            else {
                const int nr = (kshift >= 0) ? (int)(pr >> kshift) : (int)(pr / K);
                f = *(const f4*)(features + (long long)nr * DF + 4 * q);
            }
            __builtin_nontemporal_store(f, (f4*)(orow + DF + 4 * q));
        }
    }

    // FAST: prefetch pass-1 feat lines while waiting / computing pass 1
    f4 F1[4];
    if (FAST) {
#pragma unroll
        for (int m = 0; m < 4; ++m)
            F1[m] = *(const f4*)(features + (nbase + m) * DF + 32 + 4 * q);
    }

    __syncthreads();   // all pass-0 tile reads done before overwrite

    // ---- pass 1: enc cols 32..63 -> tile ----
    if (valid) {
#pragma unroll
        for (int s = 0; s < 8; ++s) {
            f4 acc = b2v[8 + s];
#pragma unroll
            for (int jj = 0; jj < HID; ++jj)
                acc += h[jj] * W2v[jj * (DF / 4) + 8 + s];
            *(f4*)&tile[wv][l][4 * (s ^ (l & 7))] = acc;
        }
    }
    __syncthreads();

    // ---- pass-1 stores: enc line1 + feat line1 of 8 rows ----
#pragma unroll
    for (int i = 0; i < 8; ++i) {
        const int r = 8 * i + g;
        const long long pr = pbase + r;
        if (FAST || pr < total) {
            float* orow = out + pr * (2 * DF);
            const f4 enc = *(const f4*)&tile[wv][r][4 * (q ^ (r & 7))];
            __builtin_nontemporal_store(enc, (f4*)(orow + 32 + 4 * q));
            f4 f;
            if (FAST) f = F1[i >> 1];
            else {
                const int nr = (kshift >= 0) ? (int)(pr >> kshift) : (int)(pr / K);
                f = *(const f4*)(features + (long long)nr * DF + 32 + 4 * q);
            }
            __builtin_nontemporal_store(f, (f4*)(orow + DF + 32 + 4 * q));
        }
    }
}

extern "C" void kernel_launch(void* const* d_in, const int* in_sizes, int n_in,
                              void* d_out, int out_size, void* d_ws, size_t ws_size,
                              hipStream_t stream) {
    const float* coords   = (const float*)d_in[0];
    const float* features = (const float*)d_in[1];
    const float* W1       = (const float*)d_in[2];
    const float* b1       = (const float*)d_in[3];
    const float* W2       = (const float*)d_in[4];
    const float* b2       = (const float*)d_in[5];
    const int*   nidx     = (const int*)d_in[6];

    const int N = in_sizes[0] / 3;              // coords (N,3)
    const int K = in_sizes[6] / N;              // neighbor_idx (N,K)
    const long long total = (long long)N * K;
    const int kshift = ((K & (K - 1)) == 0) ? __builtin_ctz(K) : -1;

    float* out = (float*)d_out;

    const int block = 256;                      // 4 waves x 64 rows
    const long long grid = (total + 255) / 256;
    if ((total & 255) == 0 && kshift == 4) {
        lse_kernel<true><<<(unsigned)grid, block, 0, stream>>>(
            coords, features, W1, b1, W2, b2, nidx, out, total, K, kshift);
    } else {
        lse_kernel<false><<<(unsigned)grid, block, 0, stream>>>(
            coords, features, W1, b1, W2, b2, nidx, out, total, K, kshift);
    }
}